// Round 1
// baseline (857.747 us; speedup 1.0000x reference)
//
#include <hip/hip_runtime.h>
#include <hip/hip_bf16.h>

// Problem constants
#define Bsz 4
#define Lseq 1024
#define OBS 60
#define DM 256
#define DI 512
#define DTR 16
#define DST 16
#define NTOK (Bsz*Lseq)   // 4096
#define NCH 32            // scan chunks per sequence
#define CH  32            // steps per chunk

__device__ __forceinline__ float silu_f(float v) {
    return v * (1.f / (1.f + __expf(-v)));
}

// ---------------- input projection + SiLU ----------------
__global__ __launch_bounds__(256) void input_proj_kernel(
    const float* __restrict__ obs, const float* __restrict__ W,
    const float* __restrict__ bias, float* __restrict__ x) {
    int t = blockIdx.x; int e = threadIdx.x;
    __shared__ float so[OBS];
    if (e < OBS) so[e] = obs[t*OBS + e];
    __syncthreads();
    float acc = bias[e];
    const float* wr = W + e*OBS;
    #pragma unroll
    for (int k = 0; k < OBS; ++k) acc += so[k]*wr[k];
    x[t*DM + e] = silu_f(acc);
}

// ---------------- layernorm (per token, D=256) ----------------
__global__ __launch_bounds__(256) void ln_kernel(
    const float* __restrict__ x, const float* __restrict__ w,
    const float* __restrict__ b, float* __restrict__ xn) {
    int t = blockIdx.x; int tid = threadIdx.x;
    float v = x[t*DM + tid];
    float s = v;
    #pragma unroll
    for (int off = 32; off; off >>= 1) s += __shfl_down(s, off);
    __shared__ float ps[4];
    __shared__ float mean_s, rstd_s;
    int wid = tid >> 6, lane = tid & 63;
    if (lane == 0) ps[wid] = s;
    __syncthreads();
    if (tid == 0) mean_s = (ps[0]+ps[1]+ps[2]+ps[3]) * (1.f/DM);
    __syncthreads();
    float m = mean_s;
    float d = v - m;
    float sq = d*d;
    #pragma unroll
    for (int off = 32; off; off >>= 1) sq += __shfl_down(sq, off);
    if (lane == 0) ps[wid] = sq;
    __syncthreads();
    if (tid == 0) rstd_s = rsqrtf((ps[0]+ps[1]+ps[2]+ps[3])*(1.f/DM) + 1e-5f);
    __syncthreads();
    xn[t*DM + tid] = d * rstd_s * w[tid] + b[tid];
}

// ---------------- tiled SGEMM: C[M,N] = A[M,K] * W[N,K]^T (+resid) ----------------
__global__ __launch_bounds__(256) void sgemm_nt(
    const float* __restrict__ A, const float* __restrict__ W,
    float* __restrict__ C, const float* __restrict__ resid,
    int M, int N, int K) {
    __shared__ __align__(16) float As[16][68];
    __shared__ __align__(16) float Bs[16][68];
    int tid = threadIdx.x;
    int lk = tid & 15;     // k within K-tile
    int lm = tid >> 4;     // 0..15
    int tr = tid >> 4;     // row group
    int tc = tid & 15;     // col group
    int row0 = blockIdx.y * 64;
    int col0 = blockIdx.x * 64;
    float acc[4][4] = {};
    for (int k0 = 0; k0 < K; k0 += 16) {
        #pragma unroll
        for (int i = 0; i < 4; ++i) {
            int m = lm + 16*i;
            As[lk][m] = A[(size_t)(row0 + m)*K + k0 + lk];
            float wv = 0.f;
            if (col0 + m < N) wv = W[(size_t)(col0 + m)*K + k0 + lk];
            Bs[lk][m] = wv;
        }
        __syncthreads();
        #pragma unroll
        for (int kk = 0; kk < 16; ++kk) {
            float4 av = *(const float4*)&As[kk][tr*4];
            float4 bv = *(const float4*)&Bs[kk][tc*4];
            float a[4] = {av.x, av.y, av.z, av.w};
            float bb[4] = {bv.x, bv.y, bv.z, bv.w};
            #pragma unroll
            for (int i = 0; i < 4; ++i)
                #pragma unroll
                for (int j = 0; j < 4; ++j)
                    acc[i][j] += a[i]*bb[j];
        }
        __syncthreads();
    }
    int n0 = col0 + tc*4;
    if (n0 < N) {
        #pragma unroll
        for (int i = 0; i < 4; ++i) {
            size_t idx = (size_t)(row0 + tr*4 + i)*N + n0;
            float4 v = make_float4(acc[i][0], acc[i][1], acc[i][2], acc[i][3]);
            if (resid) {
                float4 r = *(const float4*)&resid[idx];
                v.x += r.x; v.y += r.y; v.z += r.z; v.w += r.w;
            }
            *(float4*)&C[idx] = v;
        }
    }
}

// ---------------- causal depthwise conv (width 4) + SiLU ----------------
__global__ __launch_bounds__(256) void conv_silu_kernel(
    const float* __restrict__ xz, const float* __restrict__ cw,
    const float* __restrict__ cb, float* __restrict__ xi) {
    int idx = blockIdx.x*blockDim.x + threadIdx.x;
    if (idx >= NTOK*DI) return;
    int d = idx & (DI-1); int t = idx >> 9;
    int l = t & (Lseq-1); int b = t >> 10;
    float acc = cb[d];
    #pragma unroll
    for (int k = 0; k < 4; ++k) {
        int ls = l - 3 + k;
        if (ls >= 0) acc += xz[((size_t)(b*Lseq + ls))*(2*DI) + d] * cw[d*4 + k];
    }
    xi[idx] = silu_f(acc);
}

// ---------------- dt = softplus(dbc[:,:16] @ dtw^T + dtb) ----------------
__global__ __launch_bounds__(256) void dt_kernel(
    const float* __restrict__ dbc, const float* __restrict__ dtw,
    const float* __restrict__ dtb, float* __restrict__ dt) {
    int t = blockIdx.x; int tid = threadIdx.x;
    __shared__ float sr[DTR];
    if (tid < DTR) sr[tid] = dbc[t*48 + tid];
    __syncthreads();
    #pragma unroll
    for (int h = 0; h < 2; ++h) {
        int e = tid + h*256;
        float acc = dtb[e];
        const float* wr = dtw + e*DTR;
        #pragma unroll
        for (int r = 0; r < DTR; ++r) acc += sr[r]*wr[r];
        float sp = fmaxf(acc, 0.f) + log1pf(__expf(-fabsf(acc)));
        dt[t*DI + e] = sp;
    }
}

// ---------------- selective scan, 3-phase chunked ----------------
// summaries layout: [b][chunk][n][d]
__global__ __launch_bounds__(256) void scan_phaseA(
    const float* __restrict__ dt, const float* __restrict__ xi,
    const float* __restrict__ dbc, const float* __restrict__ a_log,
    float* __restrict__ Ap, float* __restrict__ He) {
    int blk = blockIdx.x;               // b*64 + c*2 + half
    int b = blk >> 6; int rem = blk & 63; int c = rem >> 1; int half = rem & 1;
    int d = half*256 + threadIdx.x;
    float An[16];
    #pragma unroll
    for (int n = 0; n < 16; ++n) An[n] = -__expf(a_log[d*16 + n]);
    float h[16] = {};
    float ap[16];
    #pragma unroll
    for (int n = 0; n < 16; ++n) ap[n] = 1.f;
    for (int s = 0; s < CH; ++s) {
        int t = b*Lseq + c*CH + s;
        float dtv = dt[t*DI + d];
        float xiv = xi[t*DI + d];
        float u = dtv*xiv;
        const float* Bp = dbc + t*48 + DTR;
        #pragma unroll
        for (int n = 0; n < 16; ++n) {
            float dA = __expf(dtv*An[n]);
            h[n] = dA*h[n] + u*Bp[n];
            ap[n] *= dA;
        }
    }
    size_t base = ((size_t)(b*NCH + c)*16)*DI + d;
    #pragma unroll
    for (int n = 0; n < 16; ++n) { Ap[base + n*DI] = ap[n]; He[base + n*DI] = h[n]; }
}

__global__ __launch_bounds__(256) void scan_phaseB(
    const float* __restrict__ Ap, const float* __restrict__ He,
    float* __restrict__ h0) {
    int g = blockIdx.x*blockDim.x + threadIdx.x;  // 32768 threads
    int b = g >> 13; int n = (g >> 9) & 15; int d = g & 511;
    float run = 0.f;
    for (int c = 0; c < NCH; ++c) {
        size_t idx = ((size_t)(b*NCH + c)*16 + n)*DI + d;
        h0[idx] = run;
        run = Ap[idx]*run + He[idx];
    }
}

__global__ __launch_bounds__(256) void scan_phaseC(
    const float* __restrict__ dt, const float* __restrict__ xi,
    const float* __restrict__ dbc, const float* __restrict__ a_log,
    const float* __restrict__ dskip, const float* __restrict__ xz,
    const float* __restrict__ h0, float* __restrict__ yg) {
    int blk = blockIdx.x;
    int b = blk >> 6; int rem = blk & 63; int c = rem >> 1; int half = rem & 1;
    int d = half*256 + threadIdx.x;
    float An[16];
    #pragma unroll
    for (int n = 0; n < 16; ++n) An[n] = -__expf(a_log[d*16 + n]);
    float h[16];
    size_t base = ((size_t)(b*NCH + c)*16)*DI + d;
    #pragma unroll
    for (int n = 0; n < 16; ++n) h[n] = h0[base + n*DI];
    float ds = dskip[d];
    for (int s = 0; s < CH; ++s) {
        int t = b*Lseq + c*CH + s;
        float dtv = dt[t*DI + d];
        float xiv = xi[t*DI + d];
        float u = dtv*xiv;
        const float* Bp = dbc + t*48 + DTR;
        const float* Cp = dbc + t*48 + DTR + DST;
        float y = ds*xiv;
        #pragma unroll
        for (int n = 0; n < 16; ++n) {
            float dA = __expf(dtv*An[n]);
            h[n] = dA*h[n] + u*Bp[n];
            y += h[n]*Cp[n];
        }
        float zv = xz[(size_t)t*(2*DI) + DI + d];
        yg[t*DI + d] = y * silu_f(zv);
    }
}

// ---------------- policy/value heads ----------------
__global__ __launch_bounds__(256) void heads_kernel(
    const float* __restrict__ x, const float* __restrict__ pw,
    const float* __restrict__ pb, const float* __restrict__ ls,
    const float* __restrict__ vw, const float* __restrict__ vb,
    float* __restrict__ out) {
    int t = blockIdx.x; int tid = threadIdx.x;
    float xv = x[t*DM + tid];
    float s0 = xv * pw[tid];
    float s1 = xv * pw[DM + tid];
    float s2 = xv * vw[tid];
    #pragma unroll
    for (int off = 32; off; off >>= 1) {
        s0 += __shfl_down(s0, off);
        s1 += __shfl_down(s1, off);
        s2 += __shfl_down(s2, off);
    }
    __shared__ float p0[4], p1[4], p2[4];
    int wid = tid >> 6, lane = tid & 63;
    if (lane == 0) { p0[wid]=s0; p1[wid]=s1; p2[wid]=s2; }
    __syncthreads();
    if (tid == 0) {
        float m0 = p0[0]+p0[1]+p0[2]+p0[3] + pb[0];
        float m1 = p1[0]+p1[1]+p1[2]+p1[3] + pb[1];
        float vv = p2[0]+p2[1]+p2[2]+p2[3] + vb[0];
        out[t*2 + 0] = m0;
        out[t*2 + 1] = m1;
        out[NTOK*2 + t*2 + 0] = __expf(ls[0]);
        out[NTOK*2 + t*2 + 1] = __expf(ls[1]);
        out[NTOK*4 + t] = vv;
    }
}

extern "C" void kernel_launch(void* const* d_in, const int* in_sizes, int n_in,
                              void* d_out, int out_size, void* d_ws, size_t ws_size,
                              hipStream_t stream) {
    const float* obs = (const float*)d_in[0];
    const float* ipw = (const float*)d_in[1];
    const float* ipb = (const float*)d_in[2];
    const float* nw  = (const float*)d_in[3];
    const float* nb  = (const float*)d_in[4];
    const float* inw = (const float*)d_in[5];
    const float* cw  = (const float*)d_in[6];
    const float* cb  = (const float*)d_in[7];
    const float* xw  = (const float*)d_in[8];
    const float* dtw = (const float*)d_in[9];
    const float* dtb = (const float*)d_in[10];
    const float* alog= (const float*)d_in[11];
    const float* dsk = (const float*)d_in[12];
    const float* ow  = (const float*)d_in[13];
    const float* pw  = (const float*)d_in[14];
    const float* pb  = (const float*)d_in[15];
    const float* ls  = (const float*)d_in[16];
    const float* vw  = (const float*)d_in[17];
    const float* vb  = (const float*)d_in[18];
    float* out = (float*)d_out;

    float* ws = (float*)d_ws;
    float* x   = ws;                  // 1,048,576 f
    float* xn  = x   + 1048576;       // 1,048,576 f
    float* xz  = xn  + 1048576;       // 4,194,304 f
    float* xi  = xz  + 4194304;       // 2,097,152 f
    float* dbc = xi  + 2097152;       //   196,608 f
    float* dt  = dbc + 196608;        // 2,097,152 f
    float* yg  = dt  + 2097152;       // 2,097,152 f
    float* Ap  = yg  + 2097152;       // 1,048,576 f
    float* He  = Ap  + 1048576;       // 1,048,576 f
    float* h0  = He  + 1048576;       // 1,048,576 f  (total ~64.8 MB)

    input_proj_kernel<<<NTOK, 256, 0, stream>>>(obs, ipw, ipb, x);

    for (int i = 0; i < 4; ++i) {
        ln_kernel<<<NTOK, 256, 0, stream>>>(x, nw + i*DM, nb + i*DM, xn);
        {
            dim3 g(2*DI/64, NTOK/64);
            sgemm_nt<<<g, 256, 0, stream>>>(xn, inw + (size_t)i*2*DI*DM, xz, nullptr,
                                            NTOK, 2*DI, DM);
        }
        conv_silu_kernel<<<(NTOK*DI)/256, 256, 0, stream>>>(xz, cw + i*DI*4, cb + i*DI, xi);
        {
            dim3 g(1, NTOK/64);
            sgemm_nt<<<g, 256, 0, stream>>>(xi, xw + (size_t)i*48*DI, dbc, nullptr,
                                            NTOK, 48, DI);
        }
        dt_kernel<<<NTOK, 256, 0, stream>>>(dbc, dtw + i*DI*DTR, dtb + i*DI, dt);
        scan_phaseA<<<Bsz*NCH*2, 256, 0, stream>>>(dt, xi, dbc, alog + (size_t)i*DI*DST, Ap, He);
        scan_phaseB<<<128, 256, 0, stream>>>(Ap, He, h0);
        scan_phaseC<<<Bsz*NCH*2, 256, 0, stream>>>(dt, xi, dbc, alog + (size_t)i*DI*DST,
                                                   dsk + i*DI, xz, h0, yg);
        {
            dim3 g(DM/64, NTOK/64);
            sgemm_nt<<<g, 256, 0, stream>>>(yg, ow + (size_t)i*DM*DI, x, x,
                                            NTOK, DM, DI);
        }
    }
    heads_kernel<<<NTOK, 256, 0, stream>>>(x, pw, pb, ls, vw, vb, out);
}

// Round 2
// 437.261 us; speedup vs baseline: 1.9616x; 1.9616x over previous
//
#include <hip/hip_runtime.h>
#include <hip/hip_bf16.h>

// Problem constants
#define Bsz 4
#define Lseq 1024
#define OBS 60
#define DM 256
#define DI 512
#define DTR 16
#define DST 16
#define NTOK (Bsz*Lseq)   // 4096
#define NCH 32            // scan chunks per sequence
#define CH  32            // steps per chunk

typedef _Float16 half8 __attribute__((ext_vector_type(8)));
typedef float floatx4 __attribute__((ext_vector_type(4)));

__device__ __forceinline__ float silu_f(float v) {
    return v * (1.f / (1.f + __expf(-v)));
}

// ---------------- weight conversion fp32 -> fp16 (x_proj padded 48->64) ----------------
#define NIN_W  (4*1024*256)
#define NX_W   (4*64*512)
#define NOUT_W (4*256*512)
__global__ __launch_bounds__(256) void convert_weights(
    const float* __restrict__ inw, const float* __restrict__ xw,
    const float* __restrict__ ow, _Float16* __restrict__ wh_in,
    _Float16* __restrict__ wh_x, _Float16* __restrict__ wh_out) {
    int idx = blockIdx.x*256 + threadIdx.x;
    if (idx < NIN_W) {
        wh_in[idx] = (_Float16)inw[idx];
    } else if (idx < NIN_W + NX_W) {
        int r = idx - NIN_W;
        int layer = r >> 15;          // /(64*512)
        int rem = r & 32767;
        int n = rem >> 9, k = rem & 511;
        wh_x[r] = (_Float16)((n < 48) ? xw[((size_t)layer*48 + n)*512 + k] : 0.f);
    } else if (idx < NIN_W + NX_W + NOUT_W) {
        int r = idx - NIN_W - NX_W;
        wh_out[r] = (_Float16)ow[r];
    }
}

// ---------------- input projection + SiLU ----------------
__global__ __launch_bounds__(256) void input_proj_kernel(
    const float* __restrict__ obs, const float* __restrict__ W,
    const float* __restrict__ bias, float* __restrict__ x) {
    int t = blockIdx.x; int e = threadIdx.x;
    __shared__ float so[OBS];
    if (e < OBS) so[e] = obs[t*OBS + e];
    __syncthreads();
    float acc = bias[e];
    const float* wr = W + e*OBS;
    #pragma unroll
    for (int k = 0; k < OBS; ++k) acc += so[k]*wr[k];
    x[t*DM + e] = silu_f(acc);
}

// ---------------- layernorm (per token, D=256) -> fp16 ----------------
__global__ __launch_bounds__(256) void ln_kernel(
    const float* __restrict__ x, const float* __restrict__ w,
    const float* __restrict__ b, _Float16* __restrict__ xn_h) {
    int t = blockIdx.x; int tid = threadIdx.x;
    float v = x[t*DM + tid];
    float s = v;
    #pragma unroll
    for (int off = 32; off; off >>= 1) s += __shfl_down(s, off);
    __shared__ float ps[4];
    __shared__ float mean_s, rstd_s;
    int wid = tid >> 6, lane = tid & 63;
    if (lane == 0) ps[wid] = s;
    __syncthreads();
    if (tid == 0) mean_s = (ps[0]+ps[1]+ps[2]+ps[3]) * (1.f/DM);
    __syncthreads();
    float m = mean_s;
    float d = v - m;
    float sq = d*d;
    #pragma unroll
    for (int off = 32; off; off >>= 1) sq += __shfl_down(sq, off);
    if (lane == 0) ps[wid] = sq;
    __syncthreads();
    if (tid == 0) rstd_s = rsqrtf((ps[0]+ps[1]+ps[2]+ps[3])*(1.f/DM) + 1e-5f);
    __syncthreads();
    xn_h[t*DM + tid] = (_Float16)(d * rstd_s * w[tid] + b[tid]);
}

// ---------------- fp16 MFMA GEMM: C[M,N] = A[M,K] * W[N,K]^T (+resid) ----------------
// BK=64, XOR-swizzled LDS, 4 waves in WM x WN grid.
template<int BM, int BN, int WM, int WN, bool RESID>
__global__ __launch_bounds__(256) void hgemm_nt(
    const _Float16* __restrict__ A, const _Float16* __restrict__ W,
    float* __restrict__ C, const float* __restrict__ resid,
    int M, int N, int K, int ldc) {
    constexpr int MFR = BM/(WM*16);
    constexpr int NFR = BN/(WN*16);
    __shared__ _Float16 As[BM*64];
    __shared__ _Float16 Bs[BN*64];
    int tid = threadIdx.x;
    int r0 = blockIdx.y*BM, c0 = blockIdx.x*BN;
    int w = tid >> 6, lane = tid & 63;
    int wr = w / WN, wc = w % WN;
    floatx4 acc[MFR][NFR];
    #pragma unroll
    for (int i = 0; i < MFR; ++i)
        #pragma unroll
        for (int j = 0; j < NFR; ++j)
            acc[i][j] = (floatx4)0.f;

    for (int k0 = 0; k0 < K; k0 += 64) {
        #pragma unroll
        for (int c = 0; c < BM/32; ++c) {
            int q = tid + 256*c;
            int row = q >> 3, cc = (q & 7)*8;
            half8 v = *(const half8*)&A[(size_t)(r0 + row)*K + k0 + cc];
            *(half8*)&As[row*64 + (cc ^ ((row & 7) << 3))] = v;
        }
        #pragma unroll
        for (int c = 0; c < BN/32; ++c) {
            int q = tid + 256*c;
            int row = q >> 3, cc = (q & 7)*8;
            half8 v = *(const half8*)&W[(size_t)(c0 + row)*K + k0 + cc];
            *(half8*)&Bs[row*64 + (cc ^ ((row & 7) << 3))] = v;
        }
        __syncthreads();
        #pragma unroll
        for (int kc = 0; kc < 2; ++kc) {
            half8 a[MFR], b[NFR];
            int col = kc*32 + (lane >> 4)*8;
            #pragma unroll
            for (int i = 0; i < MFR; ++i) {
                int row = wr*(BM/WM) + i*16 + (lane & 15);
                a[i] = *(const half8*)&As[row*64 + (col ^ ((row & 7) << 3))];
            }
            #pragma unroll
            for (int j = 0; j < NFR; ++j) {
                int row = wc*(BN/WN) + j*16 + (lane & 15);
                b[j] = *(const half8*)&Bs[row*64 + (col ^ ((row & 7) << 3))];
            }
            #pragma unroll
            for (int i = 0; i < MFR; ++i)
                #pragma unroll
                for (int j = 0; j < NFR; ++j)
                    acc[i][j] = __builtin_amdgcn_mfma_f32_16x16x32_f16(a[i], b[j], acc[i][j], 0, 0, 0);
        }
        __syncthreads();
    }
    // C/D mapping: col = lane&15, row = (lane>>4)*4 + reg
    #pragma unroll
    for (int i = 0; i < MFR; ++i) {
        int m0 = r0 + wr*(BM/WM) + i*16 + (lane >> 4)*4;
        #pragma unroll
        for (int j = 0; j < NFR; ++j) {
            int col = c0 + wc*(BN/WN) + j*16 + (lane & 15);
            if (col < N) {
                #pragma unroll
                for (int t = 0; t < 4; ++t) {
                    size_t idx = (size_t)(m0 + t)*ldc + col;
                    float v = acc[i][j][t];
                    if (RESID) v += resid[idx];
                    C[idx] = v;
                }
            }
        }
    }
}

// ---------------- causal depthwise conv (width 4) + SiLU -> fp16 ----------------
__global__ __launch_bounds__(256) void conv_silu_kernel(
    const float* __restrict__ xz, const float* __restrict__ cw,
    const float* __restrict__ cb, _Float16* __restrict__ xi_h) {
    int idx = blockIdx.x*blockDim.x + threadIdx.x;
    if (idx >= NTOK*DI) return;
    int d = idx & (DI-1); int t = idx >> 9;
    int l = t & (Lseq-1); int b = t >> 10;
    float acc = cb[d];
    #pragma unroll
    for (int k = 0; k < 4; ++k) {
        int ls = l - 3 + k;
        if (ls >= 0) acc += xz[((size_t)(b*Lseq + ls))*(2*DI) + d] * cw[d*4 + k];
    }
    xi_h[idx] = (_Float16)silu_f(acc);
}

// ---------------- dt = softplus(dbc[:,:16] @ dtw^T + dtb) ----------------
__global__ __launch_bounds__(256) void dt_kernel(
    const float* __restrict__ dbc, const float* __restrict__ dtw,
    const float* __restrict__ dtb, float* __restrict__ dt) {
    int t = blockIdx.x; int tid = threadIdx.x;
    __shared__ float sr[DTR];
    if (tid < DTR) sr[tid] = dbc[t*48 + tid];
    __syncthreads();
    #pragma unroll
    for (int h = 0; h < 2; ++h) {
        int e = tid + h*256;
        float acc = dtb[e];
        const float* wr = dtw + e*DTR;
        #pragma unroll
        for (int r = 0; r < DTR; ++r) acc += sr[r]*wr[r];
        float sp = fmaxf(acc, 0.f) + log1pf(__expf(-fabsf(acc)));
        dt[t*DI + e] = sp;
    }
}

// ---------------- selective scan, 3-phase chunked ----------------
__global__ __launch_bounds__(256) void scan_phaseA(
    const float* __restrict__ dt, const _Float16* __restrict__ xi_h,
    const float* __restrict__ dbc, const float* __restrict__ a_log,
    float* __restrict__ Ap, float* __restrict__ He) {
    int blk = blockIdx.x;               // b*64 + c*2 + half
    int b = blk >> 6; int rem = blk & 63; int c = rem >> 1; int half = rem & 1;
    int d = half*256 + threadIdx.x;
    float An[16];
    #pragma unroll
    for (int n = 0; n < 16; ++n) An[n] = -__expf(a_log[d*16 + n]);
    float h[16] = {};
    float ap[16];
    #pragma unroll
    for (int n = 0; n < 16; ++n) ap[n] = 1.f;
    for (int s = 0; s < CH; ++s) {
        int t = b*Lseq + c*CH + s;
        float dtv = dt[t*DI + d];
        float xiv = (float)xi_h[t*DI + d];
        float u = dtv*xiv;
        const float* Bp = dbc + t*48 + DTR;
        #pragma unroll
        for (int n = 0; n < 16; ++n) {
            float dA = __expf(dtv*An[n]);
            h[n] = dA*h[n] + u*Bp[n];
            ap[n] *= dA;
        }
    }
    size_t base = ((size_t)(b*NCH + c)*16)*DI + d;
    #pragma unroll
    for (int n = 0; n < 16; ++n) { Ap[base + n*DI] = ap[n]; He[base + n*DI] = h[n]; }
}

// NOTE: h0 may alias Ap (read before write per index)
__global__ __launch_bounds__(256) void scan_phaseB(
    const float* __restrict__ Ap, const float* __restrict__ He,
    float* __restrict__ h0) {
    int g = blockIdx.x*blockDim.x + threadIdx.x;  // 32768 threads
    int b = g >> 13; int n = (g >> 9) & 15; int d = g & 511;
    float run = 0.f;
    for (int c = 0; c < NCH; ++c) {
        size_t idx = ((size_t)(b*NCH + c)*16 + n)*DI + d;
        float a = Ap[idx], e = He[idx];
        h0[idx] = run;
        run = a*run + e;
    }
}

__global__ __launch_bounds__(256) void scan_phaseC(
    const float* __restrict__ dt, const _Float16* __restrict__ xi_h,
    const float* __restrict__ dbc, const float* __restrict__ a_log,
    const float* __restrict__ dskip, const float* __restrict__ xz,
    const float* __restrict__ h0, _Float16* __restrict__ yg_h) {
    int blk = blockIdx.x;
    int b = blk >> 6; int rem = blk & 63; int c = rem >> 1; int half = rem & 1;
    int d = half*256 + threadIdx.x;
    float An[16];
    #pragma unroll
    for (int n = 0; n < 16; ++n) An[n] = -__expf(a_log[d*16 + n]);
    float h[16];
    size_t base = ((size_t)(b*NCH + c)*16)*DI + d;
    #pragma unroll
    for (int n = 0; n < 16; ++n) h[n] = h0[base + n*DI];
    float ds = dskip[d];
    for (int s = 0; s < CH; ++s) {
        int t = b*Lseq + c*CH + s;
        float dtv = dt[t*DI + d];
        float xiv = (float)xi_h[t*DI + d];
        float u = dtv*xiv;
        const float* Bp = dbc + t*48 + DTR;
        const float* Cp = dbc + t*48 + DTR + DST;
        float y = ds*xiv;
        #pragma unroll
        for (int n = 0; n < 16; ++n) {
            float dA = __expf(dtv*An[n]);
            h[n] = dA*h[n] + u*Bp[n];
            y += h[n]*Cp[n];
        }
        float zv = xz[(size_t)t*(2*DI) + DI + d];
        yg_h[t*DI + d] = (_Float16)(y * silu_f(zv));
    }
}

// ---------------- policy/value heads ----------------
__global__ __launch_bounds__(256) void heads_kernel(
    const float* __restrict__ x, const float* __restrict__ pw,
    const float* __restrict__ pb, const float* __restrict__ ls,
    const float* __restrict__ vw, const float* __restrict__ vb,
    float* __restrict__ out) {
    int t = blockIdx.x; int tid = threadIdx.x;
    float xv = x[t*DM + tid];
    float s0 = xv * pw[tid];
    float s1 = xv * pw[DM + tid];
    float s2 = xv * vw[tid];
    #pragma unroll
    for (int off = 32; off; off >>= 1) {
        s0 += __shfl_down(s0, off);
        s1 += __shfl_down(s1, off);
        s2 += __shfl_down(s2, off);
    }
    __shared__ float p0[4], p1[4], p2[4];
    int wid = tid >> 6, lane = tid & 63;
    if (lane == 0) { p0[wid]=s0; p1[wid]=s1; p2[wid]=s2; }
    __syncthreads();
    if (tid == 0) {
        float m0 = p0[0]+p0[1]+p0[2]+p0[3] + pb[0];
        float m1 = p1[0]+p1[1]+p1[2]+p1[3] + pb[1];
        float vv = p2[0]+p2[1]+p2[2]+p2[3] + vb[0];
        out[t*2 + 0] = m0;
        out[t*2 + 1] = m1;
        out[NTOK*2 + t*2 + 0] = __expf(ls[0]);
        out[NTOK*2 + t*2 + 1] = __expf(ls[1]);
        out[NTOK*4 + t] = vv;
    }
}

extern "C" void kernel_launch(void* const* d_in, const int* in_sizes, int n_in,
                              void* d_out, int out_size, void* d_ws, size_t ws_size,
                              hipStream_t stream) {
    const float* obs = (const float*)d_in[0];
    const float* ipw = (const float*)d_in[1];
    const float* ipb = (const float*)d_in[2];
    const float* nw  = (const float*)d_in[3];
    const float* nb  = (const float*)d_in[4];
    const float* inw = (const float*)d_in[5];
    const float* cw  = (const float*)d_in[6];
    const float* cb  = (const float*)d_in[7];
    const float* xw  = (const float*)d_in[8];
    const float* dtw = (const float*)d_in[9];
    const float* dtb = (const float*)d_in[10];
    const float* alog= (const float*)d_in[11];
    const float* dsk = (const float*)d_in[12];
    const float* ow  = (const float*)d_in[13];
    const float* pw  = (const float*)d_in[14];
    const float* pb  = (const float*)d_in[15];
    const float* ls  = (const float*)d_in[16];
    const float* vw  = (const float*)d_in[17];
    const float* vb  = (const float*)d_in[18];
    float* out = (float*)d_out;

    float* ws = (float*)d_ws;
    float* x   = ws;                  // 1,048,576 f32
    float* xz  = x   + 1048576;       // 4,194,304
    float* dbc = xz  + 4194304;       //   196,608
    float* dt  = dbc + 196608;        // 2,097,152
    float* Ap  = dt  + 2097152;       // 1,048,576 (h0 aliases Ap)
    float* He  = Ap  + 1048576;       // 1,048,576
    float* h0  = Ap;                  // alias (phaseB reads before write per idx)
    _Float16* f16b  = (_Float16*)(He + 1048576);
    _Float16* xn_h  = f16b;                   // 1,048,576
    _Float16* xi_h  = xn_h  + 1048576;        // 2,097,152
    _Float16* yg_h  = xi_h  + 2097152;        // 2,097,152
    _Float16* wh_in = yg_h  + 2097152;        // 1,048,576
    _Float16* wh_x  = wh_in + 1048576;        //   131,072
    _Float16* wh_out= wh_x  + 131072;         //   524,288

    convert_weights<<<(NIN_W + NX_W + NOUT_W + 255)/256, 256, 0, stream>>>(
        inw, xw, ow, wh_in, wh_x, wh_out);
    input_proj_kernel<<<NTOK, 256, 0, stream>>>(obs, ipw, ipb, x);

    for (int i = 0; i < 4; ++i) {
        ln_kernel<<<NTOK, 256, 0, stream>>>(x, nw + i*DM, nb + i*DM, xn_h);
        {   // in_proj: M=4096, N=1024, K=256
            dim3 g(1024/128, NTOK/128);
            hgemm_nt<128,128,2,2,false><<<g, 256, 0, stream>>>(
                xn_h, wh_in + (size_t)i*1024*256, xz, nullptr, NTOK, 1024, 256, 1024);
        }
        conv_silu_kernel<<<(NTOK*DI)/256, 256, 0, stream>>>(xz, cw + i*DI*4, cb + i*DI, xi_h);
        {   // x_proj: M=4096, N=48 (padded 64), K=512
            dim3 g(1, NTOK/64);
            hgemm_nt<64,64,2,2,false><<<g, 256, 0, stream>>>(
                xi_h, wh_x + (size_t)i*64*512, dbc, nullptr, NTOK, 48, 512, 48);
        }
        dt_kernel<<<NTOK, 256, 0, stream>>>(dbc, dtw + i*DI*DTR, dtb + i*DI, dt);
        scan_phaseA<<<Bsz*NCH*2, 256, 0, stream>>>(dt, xi_h, dbc, alog + (size_t)i*DI*DST, Ap, He);
        scan_phaseB<<<128, 256, 0, stream>>>(Ap, He, h0);
        scan_phaseC<<<Bsz*NCH*2, 256, 0, stream>>>(dt, xi_h, dbc, alog + (size_t)i*DI*DST,
                                                   dsk + i*DI, xz, h0, yg_h);
        {   // out_proj: M=4096, N=256, K=512, residual add into x
            dim3 g(256/128, NTOK/64);
            hgemm_nt<64,128,2,2,true><<<g, 256, 0, stream>>>(
                yg_h, wh_out + (size_t)i*256*512, x, x, NTOK, 256, 512, 256);
        }
    }
    heads_kernel<<<NTOK, 256, 0, stream>>>(x, pw, pb, ls, vw, vb, out);
}